// Round 19
// baseline (94.262 us; speedup 1.0000x reference)
//
#include <hip/hip_runtime.h>

// MHA forward, MI355X gfx950. bf16 MFMA pipeline, fp32 accumulate.
// R19: R18 (cvt_all, gemm0 TM128/TN96 balanced, attn v18 4-blocks/CU) +
//      gemm_out: out-proj with BK=64 (12 fat windows vs 24 thin), 2-buffer
//      1-deep pipeline, XOR-swizzled staging (128B rows need it).

#define DM   768
#define SEQ  2048
#define NB   2
#define NH   12
#define DK   64
#define MROWS (NB*SEQ)                       // 4096
#define QSCALE 0.18033688011112042f          // (1/sqrt(64)) * log2(e): softmax in exp2 domain

typedef unsigned short u16;
typedef __bf16 bf16x8 __attribute__((ext_vector_type(8)));
typedef float  f32x4  __attribute__((ext_vector_type(4)));
typedef unsigned int u32x4 __attribute__((ext_vector_type(4)));

__device__ __forceinline__ u16 f2bf(float f) {      // RNE f32 -> bf16
  unsigned u = __builtin_bit_cast(unsigned, f);
  u += 0x7fffu + ((u >> 16) & 1u);
  return (u16)(u >> 16);
}

__device__ __forceinline__ unsigned cvtpk(float lo, float hi) {  // 2xbf16 pack, RNE
  unsigned r;
  asm("v_cvt_pk_bf16_f32 %0, %1, %2" : "=v"(r) : "v"(lo), "v"(hi));
  return r;
}

__device__ __forceinline__ bf16x8 ldbf8(const u16* p) {   // 16B aligned load
  return __builtin_bit_cast(bf16x8, *(const u32x4*)p);
}

__device__ __forceinline__ void gl_lds16(const void* g, void* l) {
  __builtin_amdgcn_global_load_lds((__attribute__((address_space(1))) void*)g,
                                   (__attribute__((address_space(3))) void*)l,
                                   16, 0, 0);
}

// swizzled 16B read at logical (row, byte wo) of a tile with 128B rows
__device__ __forceinline__ bf16x8 ldtile(const u16* T, int row, int wo) {
  return ldbf8((const u16*)((const char*)T + row*128 + (wo ^ ((row & 7) << 4))));
}

// ---------------- fp32 -> bf16 convert, single launch (x + 4 weights) -------
__global__ void cvt_all(const float* __restrict__ x,
                        const float* __restrict__ w0, const float* __restrict__ w1,
                        const float* __restrict__ w2, const float* __restrict__ w3,
                        u16* __restrict__ dx, u16* __restrict__ dw,
                        int nx4, int nw4) {
  const int i = blockIdx.x * blockDim.x + threadIdx.x;
  const float* s; ushort4* d; int idx;
  if (i < nx4) {
    s = x; d = (ushort4*)dx; idx = i;
  } else {
    const int j = i - nx4;
    const int m = j / nw4;
    idx = j - m * nw4;
    s = (m == 0) ? w0 : (m == 1) ? w1 : (m == 2) ? w2 : w3;
    d = (ushort4*)dw + (size_t)m * nw4;
  }
  const float4 v = ((const float4*)s)[idx];
  ushort4 rr;
  rr.x = f2bf(v.x); rr.y = f2bf(v.y); rr.z = f2bf(v.z); rr.w = f2bf(v.w);
  d[idx] = rr;
}

// ---------------- gemm_bt (QKV): TM=128, TN=96, BK=32, 2-deep (R15) ---------
__global__ __launch_bounds__(256, 3) void gemm_qkv(
    const u16* __restrict__ A,
    const u16* __restrict__ B0, const u16* __restrict__ B1, const u16* __restrict__ B2,
    const float* __restrict__ bias0, const float* __restrict__ bias1, const float* __restrict__ bias2,
    u16* __restrict__ q_out, u16* __restrict__ k_out, u16* __restrict__ vt_out)
{
  constexpr int TM = 128, TN = 96;
  constexpr int MF = TM / 32, NF = TN / 32;
  __shared__ u16 At[3][TM*32];
  __shared__ u16 Bt[3][TN*32];
  const int tid = threadIdx.x;
  const int w = tid >> 6, lane = tid & 63;
  const int lg = lane >> 4, ll = lane & 15;

  const int L = blockIdx.x;
  const int xcd = L & 7, li = L >> 3;
  const int bm = xcd*4 + li/24, bn = li%24;      // 32 bm, 24 bn
  const int row0 = bm * TM;

  const int mat = bn / 8;                        // 0=Q 1=K 2=V
  const u16* Bm = (mat == 0) ? B0 : (mat == 1) ? B1 : B2;
  const float* bias = (mat == 0) ? bias0 : (mat == 1) ? bias1 : bias2;
  const int col0 = (bn % 8) * TN;
  const int wr = w >> 1, wc = w & 1;

  f32x4 acc[MF][NF] = {};

#define GSTAGE(BUF, K0) do {                                                  \
    _Pragma("unroll")                                                         \
    for (int c = w; c < TM/16; c += 4) {                                      \
      const int a = c*1024 + lane*16;                                         \
      gl_lds16((const char*)A + ((size_t)(row0 + (a>>6))*DM + (K0))*2 + (a&63), \
               (char*)At[BUF] + c*1024);                                      \
    }                                                                         \
    _Pragma("unroll")                                                         \
    for (int c = w; c < TN/16; c += 4) {                                      \
      const int a = c*1024 + lane*16;                                         \
      gl_lds16((const char*)Bm + ((size_t)(col0 + (a>>6))*DM + (K0))*2 + (a&63), \
               (char*)Bt[BUF] + c*1024);                                      \
    }                                                                         \
  } while (0)

  GSTAGE(0, 0);
  GSTAGE(1, 32);
  int cur = 0;
  const int nsteps = DM / 32;                    // 24
#pragma unroll 1
  for (int j = 0; j < nsteps; ++j) {
    if (j + 1 < nsteps) asm volatile("s_waitcnt vmcnt(3)" ::: "memory");
    else                asm volatile("s_waitcnt vmcnt(0)" ::: "memory");
    __builtin_amdgcn_s_barrier();
    __builtin_amdgcn_sched_barrier(0);
    if (j + 2 < nsteps) {
      int nb = cur + 2; if (nb >= 3) nb -= 3;
      GSTAGE(nb, (j + 2) * 32);
    }

    bf16x8 fa[MF], fb[NF];
#pragma unroll
    for (int m = 0; m < MF; ++m)
      fa[m] = ldbf8(&At[cur][(wr*(TM/2) + m*16 + ll)*32 + lg*8]);
#pragma unroll
    for (int n = 0; n < NF; ++n)
      fb[n] = ldbf8(&Bt[cur][(wc*(TN/2) + n*16 + ll)*32 + lg*8]);
#pragma unroll
    for (int m = 0; m < MF; ++m)
#pragma unroll
      for (int n = 0; n < NF; ++n)
        acc[m][n] = __builtin_amdgcn_mfma_f32_16x16x32_bf16(fa[m], fb[n], acc[m][n], 0, 0, 0);
    cur = (cur == 2) ? 0 : cur + 1;
  }
#undef GSTAGE

#pragma unroll
  for (int m = 0; m < MF; ++m) {
#pragma unroll
    for (int n = 0; n < NF; ++n) {
      const int gn  = col0 + wc*(TN/2) + n*16 + ll;
      const float bv = bias[gn];
      const int gm0 = row0 + wr*(TM/2) + m*16 + lg*4;
#pragma unroll
      for (int j = 0; j < 4; ++j) {
        const float v = acc[m][n][j] + bv;
        const int gm = gm0 + j;
        const int b = gm >> 11, s = gm & 2047;
        const int h = gn >> 6,  d = gn & 63;
        const size_t bh = (size_t)(b*NH + h);
        if (mat == 0)      q_out[(bh*SEQ + s)*DK + d] = f2bf(v * QSCALE);
        else if (mat == 1) k_out[(bh*SEQ + s)*DK + d] = f2bf(v);
        else               vt_out[(bh*DK + d)*SEQ + s] = f2bf(v);
      }
    }
  }
}

// ---------------- gemm_out (out-proj): TM=64, TN=96, BK=64, 12 windows ------
// 2 LDS buffer sets (40960B), 1-deep: vmcnt(0) @top -> barrier -> issue
// stage(j+1) -> compute(j) (stage has a full window to land). 128B k-rows
// need the XOR swizzle (pre-swizzled gl_lds source + ldtile reads).
// Grid 512 = 8 xcd x 8 bm x 8 bn = 2 blocks/CU balanced.
__global__ __launch_bounds__(256, 2) void gemm_out(
    const u16* __restrict__ A, const u16* __restrict__ B0,
    const float* __restrict__ bias0, float* __restrict__ f_out)
{
  constexpr int MF = 2, NF = 3;                  // TM=64, TN=96
  __shared__ u16 At[2][64*64];                   // 2 x 8KB
  __shared__ u16 Bt[2][96*64];                   // 2 x 12KB
  const int tid = threadIdx.x;
  const int w = tid >> 6, lane = tid & 63;
  const int lg = lane >> 4, ll = lane & 15;

  const int L = blockIdx.x;
  const int xcd = L & 7, li = L >> 3;
  const int bm = xcd*8 + li/8, bn = li%8;        // 64 bm, 8 bn
  const int row0 = bm * 64, col0 = bn * 96;
  const int wr = w >> 1, wc = w & 1;

  f32x4 acc[MF][NF] = {};

  // swizzled staging: chunk c = 8 rows x 128B; lane slot row=a>>7,
  // source chunk-col cs = ((a>>4)&7) ^ (row&7)  (both-sides with ldtile)
#define OSTAGE(BUF, K0) do {                                                  \
    _Pragma("unroll")                                                         \
    for (int c = w; c < 8; c += 4) {                                          \
      const int a = c*1024 + lane*16;                                         \
      const int row = a >> 7;                                                 \
      const int cs = ((a >> 4) & 7) ^ (row & 7);                              \
      gl_lds16((const char*)A + ((size_t)(row0 + row)*DM + (K0))*2 + cs*16,   \
               (char*)At[BUF] + c*1024);                                      \
    }                                                                         \
    _Pragma("unroll")                                                         \
    for (int c = w; c < 12; c += 4) {                                         \
      const int a = c*1024 + lane*16;                                         \
      const int row = a >> 7;                                                 \
      const int cs = ((a >> 4) & 7) ^ (row & 7);                              \
      gl_lds16((const char*)B0 + ((size_t)(col0 + row)*DM + (K0))*2 + cs*16,  \
               (char*)Bt[BUF] + c*1024);                                      \
    }                                                                         \
  } while (0)

  OSTAGE(0, 0);
  const int nsteps = DM / 64;                    // 12
#pragma unroll 1
  for (int j = 0; j < nsteps; ++j) {
    asm volatile("s_waitcnt vmcnt(0)" ::: "memory");   // stage(j) landed
    __builtin_amdgcn_s_barrier();                // + all reads of buf[(j+1)&1] done (window j-1)
    __builtin_amdgcn_sched_barrier(0);
    if (j + 1 < nsteps) OSTAGE((j + 1) & 1, (j + 1) * 64);  // lands during compute(j)

    const u16* Ac = At[j & 1];
    const u16* Bc = Bt[j & 1];
#pragma unroll
    for (int kk = 0; kk < 2; ++kk) {
      bf16x8 fa[MF], fb[NF];
#pragma unroll
      for (int m = 0; m < MF; ++m)
        fa[m] = ldtile(Ac, wr*32 + m*16 + ll, kk*64 + lg*16);
#pragma unroll
      for (int n = 0; n < NF; ++n)
        fb[n] = ldtile(Bc, wc*48 + n*16 + ll, kk*64 + lg*16);
#pragma unroll
      for (int m = 0; m < MF; ++m)
#pragma unroll
        for (int n = 0; n < NF; ++n)
          acc[m][n] = __builtin_amdgcn_mfma_f32_16x16x32_bf16(fa[m], fb[n], acc[m][n], 0, 0, 0);
    }
  }
#undef OSTAGE

#pragma unroll
  for (int m = 0; m < MF; ++m) {
#pragma unroll
    for (int n = 0; n < NF; ++n) {
      const int gn  = col0 + wc*48 + n*16 + ll;
      const float bv = bias0[gn];
      const int gm0 = row0 + wr*32 + m*16 + lg*4;
#pragma unroll
      for (int j = 0; j < 4; ++j)
        f_out[(size_t)(gm0 + j)*DM + gn] = acc[m][n][j] + bv;
    }
  }
}

// ---------------- flash attention v18 (R18: 4 blocks/CU, slim arena) --------
__global__ __launch_bounds__(256, 4) void attn_fwd(
    const u16* __restrict__ qb, const u16* __restrict__ kb,
    const u16* __restrict__ vtb, u16* __restrict__ attb)
{
  __shared__ u16 KV[2][2][64*64];               // [dbuf][K|V] = 32KB
  __shared__ __align__(16) char arena[4608];    // Pl 4x1152 (loop) / merge (epi)
  const int L = blockIdx.x;
  const int xcd = L & 7, li = L >> 3;            // li 0..191
  const int bh = xcd*3 + (li % 3);               // XCD-clustered: 3 bh per XCD
  const int tile = 63 - li/3;                    // deep-first
  const int tid = threadIdx.x;
  const int w = tid >> 6, lane = tid & 63;
  const int c = w & 1, r = w >> 1;               // q-chunk, kv-half
  const int lg = lane >> 4, ll = lane & 15;
  const u16* qp = qb  + (size_t)bh * SEQ * DK;
  const u16* kp = kb  + (size_t)bh * SEQ * DK;
  const u16* vp = vtb + (size_t)bh * DK * SEQ;
  const int bb = bh / NH, hh = bh % NH;
  const int nt = (tile >> 1) + 1;                // KV tiles (causal)
  const int q0 = tile*32 + c*16;
  u16* Pl = (u16*)(arena + w*1152);              // 16 rows x 36 u16 per wave
  float* mg = (float*)(arena) + lane*18;         // merge slot (epilogue only)

  const bf16x8 qf0 = ldbf8(&qp[(size_t)(q0 + ll)*DK + lg*8]);
  const bf16x8 qf1 = ldbf8(&qp[(size_t)(q0 + ll)*DK + 32 + lg*8]);

  f32x4 o[4] = {};                               // lane: O[q0+ll][dt*16+lg*4+j] (own kv-half)
  float mrun = 0.f, lrun = 0.f;                  // m=0 valid: defer-thr bounds P<=2^8

#define STAGE1(T, BUF) do {                                                   \
    const char* kg_ = (const char*)kp + (size_t)(T) * 64 * 128;               \
    const char* vg_ = (const char*)vp + (size_t)(T) * 128;                    \
    _Pragma("unroll")                                                         \
    for (int j2 = 0; j2 < 4; ++j2) {                                          \
      if (w < 2) {                                                            \
        const int base = (w*4 + j2) * 1024;                                   \
        const int a = base + lane*16;                                         \
        const int row = a >> 7;                                               \
        const int cs = ((a >> 4) & 7) ^ (row & 7);                            \
        gl_lds16(kg_ + row*128 + cs*16, (char*)KV[BUF][0] + base);            \
      } else {                                                                \
        const int base = ((w-2)*4 + j2) * 1024;                               \
        const int a = base + lane*16;                                         \
        const int row = a >> 7;                                               \
        const int cs = ((a >> 4) & 7) ^ (row & 7);                            \
        gl_lds16(vg_ + (size_t)row*4096 + cs*16, (char*)KV[BUF][1] + base);   \
      }                                                                       \
    }                                                                         \
  } while (0)

  STAGE1(0, 0);                                  // prologue: tile 0 -> buf 0

#pragma unroll 1
  for (int t = 0; t < nt; ++t) {
    asm volatile("s_waitcnt vmcnt(0)" ::: "memory");   // own stage(t) landed
    __builtin_amdgcn_s_barrier();                // all stage(t) + all t-1 reads done
    __builtin_amdgcn_sched_barrier(0);
    if (t + 1 < nt) STAGE1(t + 1, (t + 1) & 1);  // lands during compute(t)

    const u16* Kt = KV[t & 1][0];
    const u16* Vt = KV[t & 1][1];

    // S^T = K_half . Q^T over d=64 (4 MFMA)
    f32x4 st[2] = {};
    __builtin_amdgcn_s_setprio(1);
#pragma unroll
    for (int kt = 0; kt < 2; ++kt) {
      const int row = r*32 + kt*16 + ll;
      st[kt] = __builtin_amdgcn_mfma_f32_16x16x32_bf16(ldtile(Kt, row, lg*16),      qf0, st[kt], 0,0,0);
      st[kt] = __builtin_amdgcn_mfma_f32_16x16x32_bf16(ldtile(Kt, row, 64 + lg*16), qf1, st[kt], 0,0,0);
    }
    __builtin_amdgcn_s_setprio(0);

    if (t == nt - 1) {                           // diagonal tile: causal mask
      const int kvb = t*64 + r*32;
#pragma unroll
      for (int kt = 0; kt < 2; ++kt)
#pragma unroll
        for (int j = 0; j < 4; ++j)
          if (kvb + kt*16 + lg*4 + j > q0 + ll) st[kt][j] = -1e30f;
    }

    float lm = -1e30f;
#pragma unroll
    for (int kt = 0; kt < 2; ++kt)
      lm = fmaxf(lm, fmaxf(fmaxf(st[kt][0], st[kt][1]), fmaxf(st[kt][2], st[kt][3])));

    if (!__all(lm <= mrun + 8.f)) {              // rare: real max growth -> rescale
      float mt = lm;
      mt = fmaxf(mt, __shfl_xor(mt, 16));
      mt = fmaxf(mt, __shfl_xor(mt, 32));
      const float mn = fmaxf(mrun, mt);
      const float sc = exp2f(mrun - mn);
      lrun *= sc;
#pragma unroll
      for (int dt = 0; dt < 4; ++dt)
#pragma unroll
        for (int j = 0; j < 4; ++j)
          o[dt][j] *= sc;
      mrun = mn;
    }

    float psum = 0.f;
    unsigned pd[4];
#pragma unroll
    for (int kt = 0; kt < 2; ++kt) {
      const float e0 = exp2f(st[kt][0] - mrun);
      const float e1 = exp2f(st[kt][1] - mrun);
      const float e2 = exp2f(st[kt][2] - mrun);
      const float e3 = exp2f(st[kt][3] - mrun);
      psum += (e0 + e1) + (e2 + e3);
      pd[kt*2]   = cvtpk(e0, e1);
      pd[kt*2+1] = cvtpk(e2, e3);
    }
    lrun += psum;                                // per-lane partial (own kv subset)

    // P repack (same-wave LDS round-trip; DS in-order within wave)
#pragma unroll
    for (int kt = 0; kt < 2; ++kt)
      *(uint2*)&Pl[ll*36 + kt*16 + lg*4] = make_uint2(pd[kt*2], pd[kt*2+1]);
    const bf16x8 pb = ldbf8(&Pl[ll*36 + lg*8]);  // P[q=ll][k_local = lg*8..+7]

    // O^T += V_half^T . P^T (K-dim = 32, 4 MFMA)
    __builtin_amdgcn_s_setprio(1);
#pragma unroll
    for (int dt = 0; dt < 4; ++dt)
      o[dt] = __builtin_amdgcn_mfma_f32_16x16x32_bf16(
                ldtile(Vt, dt*16 + ll, r*64 + lg*16), pb, o[dt], 0,0,0);
    __builtin_amdgcn_s_setprio(0);
  }
#undef STAGE1

  // per-wave row totals over own kv-half
  float lt = lrun;
  lt += __shfl_xor(lt, 16);
  lt += __shfl_xor(lt, 32);

  // merge kv-halves per chunk: (w0<-w2) chunk0, (w1<-w3) chunk1, f32 exact
#define PUBLISH() do {                                                   \
    _Pragma("unroll")                                                    \
    for (int dt = 0; dt < 4; ++dt)                                       \
      _Pragma("unroll")                                                  \
      for (int j = 0; j < 4; ++j)                                        \
        mg[dt*4 + j] = o[dt][j];                                         \
    mg[16] = mrun;                                                       \
    mg[17] = lt;                                                         \
  } while (0)
#define MERGE_STORE() do {                                               \
    const float mB = mg[16], lB = mg[17];                                \
    const float ms = fmaxf(mrun, mB);                                    \
    const float sA = exp2f(mrun - ms), sB = exp2f(mB - ms);              \
    const float li2 = 1.0f / (lt * sA + lB * sB);                        \
    u16* orow = &attb[(size_t)(bb*SEQ + q0 + ll)*DM + hh*64];            \
    _Pragma("unroll")                                                    \
    for (int dt = 0; dt < 4; ++dt) {                                     \
      ushort4 rw;                                                        \
      rw.x = f2bf((o[dt][0]*sA + mg[dt*4+0]*sB) * li2);                  \
      rw.y = f2bf((o[dt][1]*sA + mg[dt*4+1]*sB) * li2);                  \
      rw.z = f2bf((o[dt][2]*sA + mg[dt*4+2]*sB) * li2);                  \
      rw.w = f2bf((o[dt][3]*sA + mg[dt*4+3]*sB) * li2);                  \
      *(ushort4*)&orow[dt*16 + lg*4] = rw;                               \
    }                                                                    \
  } while (0)

  __syncthreads();                               // compute done; arena free
  if (w == 2) PUBLISH();
  __syncthreads();
  if (w == 0) MERGE_STORE();
  __syncthreads();
  if (w == 3) PUBLISH();
  __syncthreads();
  if (w == 1) MERGE_STORE();
#undef PUBLISH
#undef MERGE_STORE
}

// ---------------- launch ----------------
extern "C" void kernel_launch(void* const* d_in, const int* in_sizes, int n_in,
                              void* d_out, int out_size, void* d_ws, size_t ws_size,
                              hipStream_t stream) {
  const float* x  = (const float*)d_in[0];
  const float* wq = (const float*)d_in[1];
  const float* bq = (const float*)d_in[2];
  const float* wk = (const float*)d_in[3];
  const float* bk = (const float*)d_in[4];
  const float* wv = (const float*)d_in[5];
  const float* bv = (const float*)d_in[6];
  const float* wo = (const float*)d_in[7];
  const float* bo = (const float*)d_in[8];
  float* out = (float*)d_out;

  char* ws = (char*)d_ws;
  u16* xb   = (u16*)(ws);               // [4096][768]
  u16* wqb  = (u16*)(ws + 6291456);     // [768][768] x4 contiguous (wq,wk,wv,wo)
  u16* wkb  = (u16*)(ws + 7471104);
  u16* wvb  = (u16*)(ws + 8650752);
  u16* wob  = (u16*)(ws + 9830400);
  u16* qb   = (u16*)(ws + 11010048);    // [24][2048][64] scaled
  u16* kb   = (u16*)(ws + 17301504);    // [24][2048][64]
  u16* vtb  = (u16*)(ws + 23592960);    // [24][64][2048]
  u16* attb = (u16*)(ws + 29884416);    // [4096][768]

  const int nx4 = MROWS*DM/4;           // 786432
  const int nw4 = DM*DM/4;              // 147456
  const int ntot = nx4 + 4*nw4;         // 1376256 = 5376 * 256
  cvt_all<<<ntot/256, 256, 0, stream>>>(x, wq, wk, wv, wo, xb, wqb, nx4, nw4);

  gemm_qkv<<<768, 256, 0, stream>>>(xb, wqb, wkb, wvb, bq, bk, bv, qb, kb, vtb);
  attn_fwd<<<1536, 256, 0, stream>>>(qb, kb, vtb, attb);
  gemm_out<<<512, 256, 0, stream>>>(attb, wob, bo, out);
}

// Round 20
// 91.794 us; speedup vs baseline: 1.0269x; 1.0269x over previous
//
#include <hip/hip_runtime.h>

// MHA forward, MI355X gfx950. bf16 MFMA pipeline, fp32 accumulate.
// FINAL (R16 config, best measured 92.05us): cvt_all -> gemm_bt<0,128> TN=96
// balanced -> attn v16 (4-wave blocks = 2 q-chunks x 2 kv-halves, shared
// single-buffered KV tile, 6 blocks/CU, 24 waves/CU) -> gemm_bt<1,64>.

#define DM   768
#define SEQ  2048
#define NB   2
#define NH   12
#define DK   64
#define MROWS (NB*SEQ)                       // 4096
#define QSCALE 0.18033688011112042f          // (1/sqrt(64)) * log2(e): softmax in exp2 domain

typedef unsigned short u16;
typedef __bf16 bf16x8 __attribute__((ext_vector_type(8)));
typedef float  f32x4  __attribute__((ext_vector_type(4)));
typedef unsigned int u32x4 __attribute__((ext_vector_type(4)));

__device__ __forceinline__ u16 f2bf(float f) {      // RNE f32 -> bf16
  unsigned u = __builtin_bit_cast(unsigned, f);
  u += 0x7fffu + ((u >> 16) & 1u);
  return (u16)(u >> 16);
}

__device__ __forceinline__ unsigned cvtpk(float lo, float hi) {  // 2xbf16 pack, RNE
  unsigned r;
  asm("v_cvt_pk_bf16_f32 %0, %1, %2" : "=v"(r) : "v"(lo), "v"(hi));
  return r;
}

__device__ __forceinline__ bf16x8 ldbf8(const u16* p) {   // 16B aligned load
  return __builtin_bit_cast(bf16x8, *(const u32x4*)p);
}

__device__ __forceinline__ void gl_lds16(const void* g, void* l) {
  __builtin_amdgcn_global_load_lds((__attribute__((address_space(1))) void*)g,
                                   (__attribute__((address_space(3))) void*)l,
                                   16, 0, 0);
}

// ---------------- fp32 -> bf16 convert, single launch (x + 4 weights) -------
__global__ void cvt_all(const float* __restrict__ x,
                        const float* __restrict__ w0, const float* __restrict__ w1,
                        const float* __restrict__ w2, const float* __restrict__ w3,
                        u16* __restrict__ dx, u16* __restrict__ dw,
                        int nx4, int nw4) {
  const int i = blockIdx.x * blockDim.x + threadIdx.x;
  const float* s; ushort4* d; int idx;
  if (i < nx4) {
    s = x; d = (ushort4*)dx; idx = i;
  } else {
    const int j = i - nx4;
    const int m = j / nw4;
    idx = j - m * nw4;
    s = (m == 0) ? w0 : (m == 1) ? w1 : (m == 2) ? w2 : w3;
    d = (ushort4*)dw + (size_t)m * nw4;
  }
  const float4 v = ((const float4*)s)[idx];
  ushort4 rr;
  rr.x = f2bf(v.x); rr.y = f2bf(v.y); rr.z = f2bf(v.z); rr.w = f2bf(v.w);
  d[idx] = rr;
}

// ---------------- gemm_bt: C[m][n] = sum_k A[m][k]*B[n][k] ------------------
// TM x 96 tile, 2-deep pipelined (3 LDS buffer sets, counted vmcnt), linear
// grid, XCD-clustered decode, grid-balanced:
//   EPI0: TM=128, grid 768 (8 xcd x 4 bm x 24 bn) = exactly 3 blocks/CU.
//   EPI1: TM=64,  grid 512 (8 xcd x 8 bm x 8 bn)  = exactly 2 blocks/CU.
template <int EPI, int TM>
__global__ __launch_bounds__(256, 3) void gemm_bt(
    const u16* __restrict__ A,
    const u16* __restrict__ B0, const u16* __restrict__ B1, const u16* __restrict__ B2,
    const float* __restrict__ bias0, const float* __restrict__ bias1, const float* __restrict__ bias2,
    u16* __restrict__ q_out, u16* __restrict__ k_out, u16* __restrict__ vt_out,
    float* __restrict__ f_out)
{
  constexpr int TN = 96;
  constexpr int MF = TM / 32;
  constexpr int NF = TN / 32;
  __shared__ u16 At[3][TM*32];
  __shared__ u16 Bt[3][TN*32];
  const int tid = threadIdx.x;
  const int w = tid >> 6, lane = tid & 63;
  const int lg = lane >> 4, ll = lane & 15;

  const int L = blockIdx.x;
  const int xcd = L & 7, li = L >> 3;
  int bm, bn;
  if (EPI == 0) { bm = xcd*4 + li/24; bn = li%24; }    // 32 bm, 24 bn
  else          { bm = xcd*8 + li/8;  bn = li%8;  }    // 64 bm, 8 bn
  const int row0 = bm * TM;

  const u16* Bm; const float* bias; int col0; int mat = 0;
  if (EPI == 0) {
    mat  = bn / 8;                               // 0=Q 1=K 2=V
    Bm   = (mat == 0) ? B0 : (mat == 1) ? B1 : B2;
    bias = (mat == 0) ? bias0 : (mat == 1) ? bias1 : bias2;
    col0 = (bn % 8) * TN;
  } else {
    Bm = B0; bias = bias0; col0 = bn * TN;
  }
  const int wr = w >> 1, wc = w & 1;

  f32x4 acc[MF][NF] = {};

#define GSTAGE(BUF, K0) do {                                                  \
    _Pragma("unroll")                                                         \
    for (int c = w; c < TM/16; c += 4) {                                      \
      const int a = c*1024 + lane*16;                                         \
      gl_lds16((const char*)A + ((size_t)(row0 + (a>>6))*DM + (K0))*2 + (a&63), \
               (char*)At[BUF] + c*1024);                                      \
    }                                                                         \
    _Pragma("unroll")                                                         \
    for (int c = w; c < TN/16; c += 4) {                                      \
      const int a = c*1024 + lane*16;                                         \
      gl_lds16((const char*)Bm + ((size_t)(col0 + (a>>6))*DM + (K0))*2 + (a&63), \
               (char*)Bt[BUF] + c*1024);                                      \
    }                                                                         \
  } while (0)

  GSTAGE(0, 0);
  GSTAGE(1, 32);
  int cur = 0;
  const int nsteps = DM / 32;                    // 24
#pragma unroll 1
  for (int j = 0; j < nsteps; ++j) {
    if (j + 1 < nsteps) {
      if constexpr (TM == 128) asm volatile("s_waitcnt vmcnt(3)" ::: "memory");
      else                     asm volatile("s_waitcnt vmcnt(2)" ::: "memory");
    } else {
      asm volatile("s_waitcnt vmcnt(0)" ::: "memory");
    }
    __builtin_amdgcn_s_barrier();
    __builtin_amdgcn_sched_barrier(0);
    if (j + 2 < nsteps) {
      int nb = cur + 2; if (nb >= 3) nb -= 3;
      GSTAGE(nb, (j + 2) * 32);
    }

    bf16x8 fa[MF], fb[NF];
#pragma unroll
    for (int m = 0; m < MF; ++m)
      fa[m] = ldbf8(&At[cur][(wr*(TM/2) + m*16 + ll)*32 + lg*8]);
#pragma unroll
    for (int n = 0; n < NF; ++n)
      fb[n] = ldbf8(&Bt[cur][(wc*(TN/2) + n*16 + ll)*32 + lg*8]);
#pragma unroll
    for (int m = 0; m < MF; ++m)
#pragma unroll
      for (int n = 0; n < NF; ++n)
        acc[m][n] = __builtin_amdgcn_mfma_f32_16x16x32_bf16(fa[m], fb[n], acc[m][n], 0, 0, 0);
    cur = (cur == 2) ? 0 : cur + 1;
  }
#undef GSTAGE

#pragma unroll
  for (int m = 0; m < MF; ++m) {
#pragma unroll
    for (int n = 0; n < NF; ++n) {
      const int gn  = col0 + wc*(TN/2) + n*16 + ll;
      const float bv = bias[gn];
      const int gm0 = row0 + wr*(TM/2) + m*16 + lg*4;
#pragma unroll
      for (int j = 0; j < 4; ++j) {
        const float v = acc[m][n][j] + bv;
        const int gm = gm0 + j;
        if (EPI == 0) {
          const int b = gm >> 11, s = gm & 2047;
          const int h = gn >> 6,  d = gn & 63;
          const size_t bh = (size_t)(b*NH + h);
          if (mat == 0)      q_out[(bh*SEQ + s)*DK + d] = f2bf(v * QSCALE);
          else if (mat == 1) k_out[(bh*SEQ + s)*DK + d] = f2bf(v);
          else               vt_out[(bh*DK + d)*SEQ + s] = f2bf(v);
        } else {
          f_out[(size_t)gm*DM + gn] = v;
        }
      }
    }
  }
}

// ---------------- flash attention v16: shared tile, kv-split waves ----------
// grid 1536 = 8 XCD x 3 bh x 64 q-tiles (deep-first). Block = 4 waves:
// c = w&1 q-chunk (16 rows), r = w>>1 kv-half (32 kv). ONE shared KV tile
// buffer (16KB), single-buffered; all 4 waves stage 4KB each per window.
// 25.6KB LDS -> 6 blocks/CU = 24 waves/CU, all blocks resident.
// kv-half partials merged in-block through arena.

__device__ __forceinline__ bf16x8 ldtile(const u16* T, int row, int wo) {
  // swizzled 16B read at logical (row, byte-offset wo) of a [64][128B] LDS tile
  return ldbf8((const u16*)((const char*)T + row*128 + (wo ^ ((row & 7) << 4))));
}

__global__ __launch_bounds__(256, 6) void attn_fwd(
    const u16* __restrict__ qb, const u16* __restrict__ kb,
    const u16* __restrict__ vtb, u16* __restrict__ attb)
{
  __shared__ u16 Kt[64*64];                     // 8KB (kv rows x d cols)
  __shared__ u16 Vt[64*64];                     // 8KB (d rows x s cols)
  __shared__ __align__(16) char arena[9216];    // Pl 4x2304 (loop) / merge (epi)
  const int L = blockIdx.x;
  const int xcd = L & 7, li = L >> 3;            // li 0..191
  const int bh = xcd*3 + (li % 3);               // XCD-clustered: 3 bh per XCD
  const int tile = 63 - li/3;                    // deep-first
  const int tid = threadIdx.x;
  const int w = tid >> 6, lane = tid & 63;
  const int c = w & 1, r = w >> 1;               // q-chunk, kv-half
  const int lg = lane >> 4, ll = lane & 15;
  const u16* qp = qb  + (size_t)bh * SEQ * DK;
  const u16* kp = kb  + (size_t)bh * SEQ * DK;
  const u16* vp = vtb + (size_t)bh * DK * SEQ;
  const int bb = bh / NH, hh = bh % NH;
  const int nt = (tile >> 1) + 1;                // KV tiles (causal)
  const int q0 = tile*32 + c*16;
  u16* Pl = (u16*)(arena + w*2304);              // 16 rows x 72 u16 per wave
  float* mg = (float*)(arena) + lane*18;         // merge slot (epilogue only)

  const bf16x8 qf0 = ldbf8(&qp[(size_t)(q0 + ll)*DK + lg*8]);
  const bf16x8 qf1 = ldbf8(&qp[(size_t)(q0 + ll)*DK + 32 + lg*8]);

  f32x4 o[4] = {};                               // lane: O[q0+ll][dt*16+lg*4+j] (own kv-half)
  float mrun = 0.f, lrun = 0.f;                  // m=0 valid: defer-thr bounds P<=2^8

  // wave w stages 4 x 1KB chunks: w<2 -> K chunks w*4..+3; else V chunks
#define STAGE1(T) do {                                                        \
    const char* kg_ = (const char*)kp + (size_t)(T) * 64 * 128;               \
    const char* vg_ = (const char*)vp + (size_t)(T) * 128;                    \
    _Pragma("unroll")                                                         \
    for (int j2 = 0; j2 < 4; ++j2) {                                          \
      if (w < 2) {                                                            \
        const int base = (w*4 + j2) * 1024;                                   \
        const int a = base + lane*16;                                         \
        const int row = a >> 7;                                               \
        const int cs = ((a >> 4) & 7) ^ (row & 7);                            \
        gl_lds16(kg_ + row*128 + cs*16, (char*)Kt + base);                    \
      } else {                                                                \
        const int base = ((w-2)*4 + j2) * 1024;                               \
        const int a = base + lane*16;                                         \
        const int row = a >> 7;                                               \
        const int cs = ((a >> 4) & 7) ^ (row & 7);                            \
        gl_lds16(vg_ + (size_t)row*4096 + cs*16, (char*)Vt + base);           \
      }                                                                       \
    }                                                                         \
  } while (0)

  STAGE1(0);

#pragma unroll 1
  for (int t = 0; t < nt; ++t) {
    asm volatile("s_waitcnt vmcnt(0)" ::: "memory");   // own stage drained
    __builtin_amdgcn_s_barrier();                // all waves' stage landed
    __builtin_amdgcn_sched_barrier(0);

    // S^T = K_half . Q^T over d=64 (4 MFMA)
    f32x4 st[2] = {};
    __builtin_amdgcn_s_setprio(1);
#pragma unroll
    for (int kt = 0; kt < 2; ++kt) {
      const int row = r*32 + kt*16 + ll;
      st[kt] = __builtin_amdgcn_mfma_f32_16x16x32_bf16(ldtile(Kt, row, lg*16),      qf0, st[kt], 0,0,0);
      st[kt] = __builtin_amdgcn_mfma_f32_16x16x32_bf16(ldtile(Kt, row, 64 + lg*16), qf1, st[kt], 0,0,0);
    }
    __builtin_amdgcn_s_setprio(0);

    if (t == nt - 1) {                           // diagonal tile: causal mask
      const int kvb = t*64 + r*32;
#pragma unroll
      for (int kt = 0; kt < 2; ++kt)
#pragma unroll
        for (int j = 0; j < 4; ++j)
          if (kvb + kt*16 + lg*4 + j > q0 + ll) st[kt][j] = -1e30f;
    }

    float lm = -1e30f;
#pragma unroll
    for (int kt = 0; kt < 2; ++kt)
      lm = fmaxf(lm, fmaxf(fmaxf(st[kt][0], st[kt][1]), fmaxf(st[kt][2], st[kt][3])));

    if (!__all(lm <= mrun + 8.f)) {              // rare: real max growth -> rescale
      float mt = lm;
      mt = fmaxf(mt, __shfl_xor(mt, 16));
      mt = fmaxf(mt, __shfl_xor(mt, 32));
      const float mn = fmaxf(mrun, mt);
      const float sc = exp2f(mrun - mn);
      lrun *= sc;
#pragma unroll
      for (int dt = 0; dt < 4; ++dt)
#pragma unroll
        for (int j = 0; j < 4; ++j)
          o[dt][j] *= sc;
      mrun = mn;
    }

    float psum = 0.f;
    unsigned pd[4];
#pragma unroll
    for (int kt = 0; kt < 2; ++kt) {
      const float e0 = exp2f(st[kt][0] - mrun);
      const float e1 = exp2f(st[kt][1] - mrun);
      const float e2 = exp2f(st[kt][2] - mrun);
      const float e3 = exp2f(st[kt][3] - mrun);
      psum += (e0 + e1) + (e2 + e3);
      pd[kt*2]   = cvtpk(e0, e1);
      pd[kt*2+1] = cvtpk(e2, e3);
    }
    lrun += psum;                                // per-lane partial (own kv subset)

    // P repack (same-wave LDS round-trip; DS in-order within wave)
#pragma unroll
    for (int kt = 0; kt < 2; ++kt)
      *(uint2*)&Pl[ll*72 + kt*16 + lg*4] = make_uint2(pd[kt*2], pd[kt*2+1]);
    const bf16x8 pb = ldbf8(&Pl[ll*72 + lg*8]);  // P[q=ll][k_local = lg*8..+7]

    // O^T += V_half^T . P^T (K-dim = 32, 4 MFMA)
    __builtin_amdgcn_s_setprio(1);
#pragma unroll
    for (int dt = 0; dt < 4; ++dt)
      o[dt] = __builtin_amdgcn_mfma_f32_16x16x32_bf16(
                ldtile(Vt, dt*16 + ll, r*64 + lg*16), pb, o[dt], 0,0,0);
    __builtin_amdgcn_s_setprio(0);

    __builtin_amdgcn_s_barrier();                // ALL waves' reads of Kt/Vt done
    if (t + 1 < nt) STAGE1(t + 1);               // restage same buffer
  }
#undef STAGE1

  // per-wave row totals over own kv-half (sum the 4 lane-groups)
  float lt = lrun;
  lt += __shfl_xor(lt, 16);
  lt += __shfl_xor(lt, 32);

  // merge kv-halves per chunk: (w0<-w2) chunk0, (w1<-w3) chunk1, f32 exact
#define PUBLISH() do {                                                   \
    _Pragma("unroll")                                                    \
    for (int dt = 0; dt < 4; ++dt)                                       \
      _Pragma("unroll")                                                  \
      for (int j = 0; j < 4; ++j)                                        \
        mg[dt*4 + j] = o[dt][j];                                         \
    mg[16] = mrun;                                                       \
    mg[17] = lt;                                                         \
  } while (0)
#define MERGE_STORE() do {                                               \
    const float mB = mg[16], lB = mg[17];                                \
    const float ms = fmaxf(mrun, mB);                                    \
    const float sA = exp2f(mrun - ms), sB = exp2f(mB - ms);              \
    const float li2 = 1.0f / (lt * sA + lB * sB);                        \
    u16* orow = &attb[(size_t)(bb*SEQ + q0 + ll)*DM + hh*64];            \
    _Pragma("unroll")                                                    \
    for (int dt = 0; dt < 4; ++dt) {                                     \
      ushort4 rw;                                                        \
      rw.x = f2bf((o[dt][0]*sA + mg[dt*4+0]*sB) * li2);                  \
      rw.y = f2bf((o[dt][1]*sA + mg[dt*4+1]*sB) * li2);                  \
      rw.z = f2bf((o[dt][2]*sA + mg[dt*4+2]*sB) * li2);                  \
      rw.w = f2bf((o[dt][3]*sA + mg[dt*4+3]*sB) * li2);                  \
      *(ushort4*)&orow[dt*16 + lg*4] = rw;                               \
    }                                                                    \
  } while (0)

  __syncthreads();                               // compute done; arena free
  if (w == 2) PUBLISH();
  __syncthreads();
  if (w == 0) MERGE_STORE();
  __syncthreads();
  if (w == 3) PUBLISH();
  __syncthreads();
  if (w == 1) MERGE_STORE();
#undef PUBLISH
#undef MERGE_STORE
}

// ---------------- launch ----------------
extern "C" void kernel_launch(void* const* d_in, const int* in_sizes, int n_in,
                              void* d_out, int out_size, void* d_ws, size_t ws_size,
                              hipStream_t stream) {
  const float* x  = (const float*)d_in[0];
  const float* wq = (const float*)d_in[1];
  const float* bq = (const float*)d_in[2];
  const float* wk = (const float*)d_in[3];
  const float* bk = (const float*)d_in[4];
  const float* wv = (const float*)d_in[5];
  const float* bv = (const float*)d_in[6];
  const float* wo = (const float*)d_in[7];
  const float* bo = (const float*)d_in[8];
  float* out = (float*)d_out;

  char* ws = (char*)d_ws;
  u16* xb   = (u16*)(ws);               // [4096][768]
  u16* wqb  = (u16*)(ws + 6291456);     // [768][768] x4 contiguous (wq,wk,wv,wo)
  u16* wkb  = (u16*)(ws + 7471104);
  u16* wvb  = (u16*)(ws + 8650752);
  u16* wob  = (u16*)(ws + 9830400);
  u16* qb   = (u16*)(ws + 11010048);    // [24][2048][64] scaled
  u16* kb   = (u16*)(ws + 17301504);    // [24][2048][64]
  u16* vtb  = (u16*)(ws + 23592960);    // [24][64][2048]
  u16* attb = (u16*)(ws + 29884416);    // [4096][768]

  const int nx4 = MROWS*DM/4;           // 786432
  const int nw4 = DM*DM/4;              // 147456
  const int ntot = nx4 + 4*nw4;         // 1376256 = 5376 * 256
  cvt_all<<<ntot/256, 256, 0, stream>>>(x, wq, wk, wv, wo, xb, wqb, nx4, nw4);

  gemm_bt<0,128><<<768, 256, 0, stream>>>(xb, wqb, wkb, wvb, bq, bk, bv,
                                          qb, kb, vtb, nullptr);
  attn_fwd<<<1536, 256, 0, stream>>>(qb, kb, vtb, attb);
  gemm_bt<1,64><<<512, 256, 0, stream>>>(attb, wob, nullptr, nullptr, bo, nullptr, nullptr,
                                         nullptr, nullptr, nullptr, out);
}